// Round 1
// baseline (584.904 us; speedup 1.0000x reference)
//
#include <hip/hip_runtime.h>
#include <hip/hip_bf16.h>
#include <cstdio>

// LoRALinear: out[M,N] = x[M,K] @ W[N,K]^T + bias, W = base + (16/8)*(lora_B @ lora_A)
// M=8192, N=4096, K=4096 (fp32 in/out; internal bf16 MFMA).
// R5: prep was ~249us of the 554us total (inferred: gemm dispatches are ~305us; dur=554)
// at ~1.2 TB/s vs ~6.3 achievable. Split prep into two grid-stride kernels:
//   prep_x: pure fp32->bf16 stream, 8 elem/thread/step, 16B stores, 2048 blocks.
//   prep_w: block-per-row; lora_B row in uniform registers (scalar loads), rank-8 loop
//           fully unrolled, 8 cols/thread/step, 16B stores. A (128KB) is L2-resident.
// GEMM kept byte-identical to R4 (901 TF, 0 LDS conflicts) for clean attribution.

using bf16   = __bf16;
using bf16x4 = __attribute__((ext_vector_type(4))) __bf16;
using bf16x8 = __attribute__((ext_vector_type(8))) __bf16;
using f32x4  = __attribute__((ext_vector_type(4))) float;

#define TM 128
#define TN 128
#define BK 64

// ---------------- kernel 1a: x fp32 -> bf16 stream convert ----------------
__global__ __launch_bounds__(256) void prep_x(const float* __restrict__ x,
                                              bf16* __restrict__ Xb, long n8) {
    const long stride = (long)gridDim.x * blockDim.x;
    for (long i = (long)blockIdx.x * blockDim.x + threadIdx.x; i < n8; i += stride) {
        const float4 a = reinterpret_cast<const float4*>(x)[2 * i];
        const float4 b = reinterpret_cast<const float4*>(x)[2 * i + 1];
        bf16x8 o;
        o[0] = (bf16)a.x; o[1] = (bf16)a.y; o[2] = (bf16)a.z; o[3] = (bf16)a.w;
        o[4] = (bf16)b.x; o[5] = (bf16)b.y; o[6] = (bf16)b.z; o[7] = (bf16)b.w;
        reinterpret_cast<bf16x8*>(Xb)[i] = o;
    }
}

// ---------------- kernel 1b: W = base + scale*(B@A), fp32 -> bf16 ----------------
// One block per output row o. B[o][0..rank) is block-uniform -> scalar regs.
__global__ __launch_bounds__(256) void prep_w(const float* __restrict__ base,
                                              const float* __restrict__ A,
                                              const float* __restrict__ Bm,
                                              bf16* __restrict__ Wb,
                                              int K, int rank, float scale) {
    const int o = blockIdx.x;
    float br[8];
    const int rr = rank < 8 ? rank : 8;
    for (int r = 0; r < rr; ++r) br[r] = scale * Bm[(size_t)o * rank + r];

    const float* brow = base + (size_t)o * K;
    bf16*        wrow = Wb + (size_t)o * K;

    for (int c = threadIdx.x * 8; c < K; c += 256 * 8) {
        float4 s0 = *reinterpret_cast<const float4*>(brow + c);
        float4 s1 = *reinterpret_cast<const float4*>(brow + c + 4);
        if (rank == 8) {
#pragma unroll
            for (int r = 0; r < 8; ++r) {
                const float4 a0 = *reinterpret_cast<const float4*>(A + (size_t)r * K + c);
                const float4 a1 = *reinterpret_cast<const float4*>(A + (size_t)r * K + c + 4);
                s0.x += br[r] * a0.x; s0.y += br[r] * a0.y;
                s0.z += br[r] * a0.z; s0.w += br[r] * a0.w;
                s1.x += br[r] * a1.x; s1.y += br[r] * a1.y;
                s1.z += br[r] * a1.z; s1.w += br[r] * a1.w;
            }
        } else {
            for (int r = 0; r < rank; ++r) {
                const float b = scale * Bm[(size_t)o * rank + r];
                const float4 a0 = *reinterpret_cast<const float4*>(A + (size_t)r * K + c);
                const float4 a1 = *reinterpret_cast<const float4*>(A + (size_t)r * K + c + 4);
                s0.x += b * a0.x; s0.y += b * a0.y; s0.z += b * a0.z; s0.w += b * a0.w;
                s1.x += b * a1.x; s1.y += b * a1.y; s1.z += b * a1.z; s1.w += b * a1.w;
            }
        }
        bf16x8 ov;
        ov[0] = (bf16)s0.x; ov[1] = (bf16)s0.y; ov[2] = (bf16)s0.z; ov[3] = (bf16)s0.w;
        ov[4] = (bf16)s1.x; ov[5] = (bf16)s1.y; ov[6] = (bf16)s1.z; ov[7] = (bf16)s1.w;
        *reinterpret_cast<bf16x8*>(wrow + c) = ov;
    }
}

// ---------------- kernel 2: bf16 GEMM, C = X @ W^T + bias, XOR-swizzled LDS ----------------
// (byte-identical to R4) LDS tile 128 rows x 8 chunks (16B); global chunk (row,c8) stored
// at (row, c8^(row&7)). 4 waves in 2x2; each wave 4x4 blocks of 16x16x32 MFMA.
__global__ __launch_bounds__(256) void gemm_bt_bf16(
    const bf16* __restrict__ Xb,    // [M,K] row-major
    const bf16* __restrict__ Wb,    // [N,K] row-major
    const float* __restrict__ bias, // [N]
    float* __restrict__ out,        // [M,N] row-major fp32
    int M, int N, int K)
{
    __shared__ __align__(16) bf16 As[TM * BK];
    __shared__ __align__(16) bf16 Bs[TN * BK];

    const int tid  = threadIdx.x;
    const int lane = tid & 63;
    const int wv   = tid >> 6;        // wave 0..3
    const int wm   = wv >> 1;         // 2x2 wave grid over the 128x128 tile
    const int wn   = wv & 1;
    const int m0   = blockIdx.y * TM;
    const int n0   = blockIdx.x * TN;

    const int r16 = lane & 15;        // row-in-16 for A/B frags, col for C/D
    const int q   = lane >> 4;        // quad 0..3
    const int xv  = r16 & 7;          // XOR swizzle value for fragment reads

    // Staging source swizzle: lane covers LDS chunk grp*64+lane.
    const int srow = lane >> 3;                     // row offset within 8-row group
    const int scol = ((lane & 7) ^ (srow & 7)) * 8; // swizzled global column (elems)

    // ---- hoist: global staging pointers (advance by BK per iter) ----
    const bf16* gA[4];
    const bf16* gB[4];
#pragma unroll
    for (int i = 0; i < 4; ++i) {
        const int grp = i * 4 + wv;
        const int row = grp * 8 + srow;
        gA[i] = Xb + (size_t)(m0 + row) * K + scol;
        gB[i] = Wb + (size_t)(n0 + row) * K + scol;
    }

    // ---- hoist: k-invariant LDS fragment offsets (element indices) ----
    int ao[2][4], bo[2][4];
#pragma unroll
    for (int ks = 0; ks < 2; ++ks) {
        const int off = ((ks * 4 + q) ^ xv) * 8;    // swizzled element offset in row
#pragma unroll
        for (int t = 0; t < 4; ++t) {
            ao[ks][t] = (wm * 64 + t * 16 + r16) * BK + off;
            bo[ks][t] = (wn * 64 + t * 16 + r16) * BK + off;
        }
    }

    f32x4 acc[4][4] = {};

    for (int k0 = 0; k0 < K; k0 += BK) {
#pragma unroll
        for (int i = 0; i < 4; ++i) {
            const int grp = i * 4 + wv;             // wave-uniform
            __builtin_amdgcn_global_load_lds(
                (const __attribute__((address_space(1))) void*)gA[i],
                (__attribute__((address_space(3))) void*)(As + grp * 512),
                16, 0, 0);
            __builtin_amdgcn_global_load_lds(
                (const __attribute__((address_space(1))) void*)gB[i],
                (__attribute__((address_space(3))) void*)(Bs + grp * 512),
                16, 0, 0);
            gA[i] += BK;
            gB[i] += BK;
        }
        __syncthreads();

#pragma unroll
        for (int ks = 0; ks < 2; ++ks) {
            bf16x8 afrag[4], bfrag[4];
#pragma unroll
            for (int t = 0; t < 4; ++t) {
                afrag[t] = *reinterpret_cast<const bf16x8*>(&As[ao[ks][t]]);
                bfrag[t] = *reinterpret_cast<const bf16x8*>(&Bs[bo[ks][t]]);
            }
#pragma unroll
            for (int mi = 0; mi < 4; ++mi)
#pragma unroll
                for (int ni = 0; ni < 4; ++ni)
                    acc[mi][ni] = __builtin_amdgcn_mfma_f32_16x16x32_bf16(
                        afrag[mi], bfrag[ni], acc[mi][ni], 0, 0, 0);
        }
        __syncthreads();
    }

    // ---- epilogue: C/D layout col=lane&15, row=q*4+r; add bias; fp32 store ----
#pragma unroll
    for (int mi = 0; mi < 4; ++mi) {
#pragma unroll
        for (int ni = 0; ni < 4; ++ni) {
            const int gr = m0 + wm * 64 + mi * 16 + q * 4;
            const int gc = n0 + wn * 64 + ni * 16 + r16;
            const float bv = bias[gc];
#pragma unroll
            for (int r = 0; r < 4; ++r)
                out[(size_t)(gr + r) * N + gc] = acc[mi][ni][r] + bv;
        }
    }
}

extern "C" void kernel_launch(void* const* d_in, const int* in_sizes, int n_in,
                              void* d_out, int out_size, void* d_ws, size_t ws_size,
                              hipStream_t stream) {
    const float* x    = (const float*)d_in[0];
    const float* base = (const float*)d_in[1];
    const float* lA   = (const float*)d_in[2];
    const float* lB   = (const float*)d_in[3];
    const float* bias = (const float*)d_in[4];
    float* out = (float*)d_out;

    const int  N    = in_sizes[4];             // d_out = 4096
    const int  rank = in_sizes[3] / N;         // 8
    const int  K    = in_sizes[2] / rank;      // d_in = 4096
    const long M    = (long)in_sizes[0] / K;   // 8192
    const float scale = 16.0f / (float)rank;   // alpha/rank = 2.0

    bf16* Xb = (bf16*)d_ws;
    bf16* Wb = Xb + (size_t)M * K;
    const size_t need = ((size_t)M * K + (size_t)N * K) * sizeof(bf16);
    if (ws_size < need) {
        fprintf(stderr, "kernel_launch: ws_size %zu < needed %zu\n", ws_size, need);
        return;
    }

    // x convert: grid-stride, 8 floats/thread/step
    const long n8x = (long)M * K / 8;
    long blk = (n8x + 255) / 256;
    if (blk > 2048) blk = 2048;
    prep_x<<<dim3((unsigned)blk), dim3(256), 0, stream>>>(x, Xb, n8x);

    // W build: one block per output row
    prep_w<<<dim3((unsigned)N), dim3(256), 0, stream>>>(base, lA, lB, Wb, K, rank, scale);

    gemm_bt_bf16<<<dim3(N / TN, (unsigned)(M / TM)), dim3(256), 0, stream>>>(
        Xb, Wb, bias, out, (int)M, N, K);
}

// Round 2
// 542.915 us; speedup vs baseline: 1.0773x; 1.0773x over previous
//
#include <hip/hip_runtime.h>
#include <hip/hip_bf16.h>
#include <cstdio>

// LoRALinear: out[M,N] = x[M,K] @ W[N,K]^T + bias, W = base + (16/8)*(lora_B @ lora_A)
// M=8192, N=4096, K=4096 (fp32 in/out; internal bf16 MFMA).
// R6: GEMM measured 881 TF = the m97-structure ceiling (MfmaUtil 41%). Port to the
// 256x256 8-phase counted-vmcnt template (T2+T3+T4+T5): BM=BN=256, BK=64 as 2 K-slabs
// of 32; LDS [2buf][2slab][256][32] so staging granularity == phase consumption; raw
// s_barrier (no vmcnt-0 drain); vmcnt(4) twice/tile per the issue/consume ledger.
// Preps frozen from R5 (split preps changed nothing -> residual ~270us is not prep BW).

using bf16   = __bf16;
using bf16x8 = __attribute__((ext_vector_type(8))) __bf16;
using f32x4  = __attribute__((ext_vector_type(4))) float;

#define BM 256
#define BN 256
#define BK 64   // two K-slabs of 32

// ---------------- kernel 1a: x fp32 -> bf16 stream convert ----------------
__global__ __launch_bounds__(256) void prep_x(const float* __restrict__ x,
                                              bf16* __restrict__ Xb, long n8) {
    const long stride = (long)gridDim.x * blockDim.x;
    for (long i = (long)blockIdx.x * blockDim.x + threadIdx.x; i < n8; i += stride) {
        const float4 a = reinterpret_cast<const float4*>(x)[2 * i];
        const float4 b = reinterpret_cast<const float4*>(x)[2 * i + 1];
        bf16x8 o;
        o[0] = (bf16)a.x; o[1] = (bf16)a.y; o[2] = (bf16)a.z; o[3] = (bf16)a.w;
        o[4] = (bf16)b.x; o[5] = (bf16)b.y; o[6] = (bf16)b.z; o[7] = (bf16)b.w;
        reinterpret_cast<bf16x8*>(Xb)[i] = o;
    }
}

// ---------------- kernel 1b: W = base + scale*(B@A), fp32 -> bf16 ----------------
__global__ __launch_bounds__(256) void prep_w(const float* __restrict__ base,
                                              const float* __restrict__ A,
                                              const float* __restrict__ Bm,
                                              bf16* __restrict__ Wb,
                                              int K, int rank, float scale) {
    const int o = blockIdx.x;
    float br[8];
    const int rr = rank < 8 ? rank : 8;
    for (int r = 0; r < rr; ++r) br[r] = scale * Bm[(size_t)o * rank + r];

    const float* brow = base + (size_t)o * K;
    bf16*        wrow = Wb + (size_t)o * K;

    for (int c = threadIdx.x * 8; c < K; c += 256 * 8) {
        float4 s0 = *reinterpret_cast<const float4*>(brow + c);
        float4 s1 = *reinterpret_cast<const float4*>(brow + c + 4);
        if (rank == 8) {
#pragma unroll
            for (int r = 0; r < 8; ++r) {
                const float4 a0 = *reinterpret_cast<const float4*>(A + (size_t)r * K + c);
                const float4 a1 = *reinterpret_cast<const float4*>(A + (size_t)r * K + c + 4);
                s0.x += br[r] * a0.x; s0.y += br[r] * a0.y;
                s0.z += br[r] * a0.z; s0.w += br[r] * a0.w;
                s1.x += br[r] * a1.x; s1.y += br[r] * a1.y;
                s1.z += br[r] * a1.z; s1.w += br[r] * a1.w;
            }
        } else {
            for (int r = 0; r < rank; ++r) {
                const float b = scale * Bm[(size_t)o * rank + r];
                const float4 a0 = *reinterpret_cast<const float4*>(A + (size_t)r * K + c);
                const float4 a1 = *reinterpret_cast<const float4*>(A + (size_t)r * K + c + 4);
                s0.x += b * a0.x; s0.y += b * a0.y; s0.z += b * a0.z; s0.w += b * a0.w;
                s1.x += b * a1.x; s1.y += b * a1.y; s1.z += b * a1.z; s1.w += b * a1.w;
            }
        }
        bf16x8 ov;
        ov[0] = (bf16)s0.x; ov[1] = (bf16)s0.y; ov[2] = (bf16)s0.z; ov[3] = (bf16)s0.w;
        ov[4] = (bf16)s1.x; ov[5] = (bf16)s1.y; ov[6] = (bf16)s1.z; ov[7] = (bf16)s1.w;
        *reinterpret_cast<bf16x8*>(wrow + c) = ov;
    }
}

// ---------------- kernel 2: 256x256 8-phase bf16 GEMM, C = X @ W^T + bias ----------------
// LDS per matrix: [2 buf][2 kslab][256 rows][32 elems]; slab = 16KiB, staged by
// 2 global_load_lds x 16B per thread (linear dest). Swizzle: 16B chunk c of row r
// lives at slot c^((r>>1)&3) (source pre-swizzled). 8 waves 2Mx4N; per-wave C 128x64.
// Phase (ks,mh): 16 MFMA on acc[mh*4..+4][0..4] with slab ks; B-frags read at mh=0, reused.
__global__ __launch_bounds__(512, 2) void gemm_8ph(
    const bf16* __restrict__ Xb,    // [M,K] row-major
    const bf16* __restrict__ Wb,    // [N,K] row-major
    const float* __restrict__ bias, // [N]
    float* __restrict__ out,        // [M,N] row-major fp32
    int M, int N, int K)
{
    __shared__ __align__(16) bf16 As[2 * 2 * 256 * 32];  // 64 KiB
    __shared__ __align__(16) bf16 Bs[2 * 2 * 256 * 32];  // 64 KiB

    const int tid  = threadIdx.x;     // 0..511
    const int lane = tid & 63;
    const int wv   = tid >> 6;        // wave 0..7
    const int wm   = wv >> 2;         // 0..1
    const int wn   = wv & 3;          // 0..3
    const int m0   = blockIdx.y * BM;
    const int n0   = blockIdx.x * BN;

    const int r16 = lane & 15;        // row-in-16 for frags; col for C/D
    const int q   = lane >> 4;        // quad 0..3 -> K-chunk within slab
    const int cq  = (q ^ ((r16 >> 1) & 3)) * 8;  // swizzled elem offset in 32-wide row

    // ---- staging: slot(i)=i*512+tid; row=slot>>2; src chunk c = (tid&3)^((row>>1)&3)
    const bf16* srcA[2];
    const bf16* srcB[2];
#pragma unroll
    for (int i = 0; i < 2; ++i) {
        const int slot = i * 512 + tid;
        const int row  = slot >> 2;
        const int c    = (tid & 3) ^ ((row >> 1) & 3);
        srcA[i] = Xb + (size_t)(m0 + row) * K + c * 8;
        srcB[i] = Wb + (size_t)(n0 + row) * K + c * 8;
    }
    // wave-uniform LDS dest element offsets (within a slab): (i*512 + wv*64)*8 + lane*8
    const int dst0 = (0 * 512 + wv * 64) * 8;
    const int dst1 = (1 * 512 + wv * 64) * 8;

#define STAGE_A(buf, kh, koff)                                                        \
    do {                                                                              \
        __builtin_amdgcn_global_load_lds(                                             \
            (const __attribute__((address_space(1))) void*)(srcA[0] + (koff) + (kh) * 32), \
            (__attribute__((address_space(3))) void*)(As + (buf) * 16384 + (kh) * 8192 + dst0), \
            16, 0, 0);                                                                \
        __builtin_amdgcn_global_load_lds(                                             \
            (const __attribute__((address_space(1))) void*)(srcA[1] + (koff) + (kh) * 32), \
            (__attribute__((address_space(3))) void*)(As + (buf) * 16384 + (kh) * 8192 + dst1), \
            16, 0, 0);                                                                \
    } while (0)
#define STAGE_B(buf, kh, koff)                                                        \
    do {                                                                              \
        __builtin_amdgcn_global_load_lds(                                             \
            (const __attribute__((address_space(1))) void*)(srcB[0] + (koff) + (kh) * 32), \
            (__attribute__((address_space(3))) void*)(Bs + (buf) * 16384 + (kh) * 8192 + dst0), \
            16, 0, 0);                                                                \
        __builtin_amdgcn_global_load_lds(                                             \
            (const __attribute__((address_space(1))) void*)(srcB[1] + (koff) + (kh) * 32), \
            (__attribute__((address_space(3))) void*)(Bs + (buf) * 16384 + (kh) * 8192 + dst1), \
            16, 0, 0);                                                                \
    } while (0)

    // ---- k-invariant fragment element offsets (within a slab) ----
    int aoff[2][4], boff[4];
#pragma unroll
    for (int mh = 0; mh < 2; ++mh)
#pragma unroll
        for (int f = 0; f < 4; ++f)
            aoff[mh][f] = (wm * 128 + mh * 64 + f * 16 + r16) * 32 + cq;
#pragma unroll
    for (int f = 0; f < 4; ++f)
        boff[f] = (wn * 64 + f * 16 + r16) * 32 + cq;

    f32x4 acc[8][4] = {};

    // ---- prologue: tile 0 -> buf0; need slab0 landed, slab1 may stay in flight ----
    STAGE_A(0, 0, 0);
    STAGE_B(0, 0, 0);
    STAGE_A(0, 1, 0);
    STAGE_B(0, 1, 0);
    asm volatile("s_waitcnt vmcnt(4)" ::: "memory");
    __builtin_amdgcn_s_barrier();

    const int NT = K / BK;
    for (int t = 0; t < NT; ++t) {
        const int cur  = t & 1;
        const int nxt  = cur ^ 1;
        const int koff = (t + 1) * BK;
        const bool pre = (t + 1 < NT);
        bf16x8 bf[4], af[4];

        // ================= phase 0: ks=0, mh=0 =================
        {
            const bf16* Ab = As + cur * 16384;
            const bf16* Bb = Bs + cur * 16384;
#pragma unroll
            for (int f = 0; f < 4; ++f) bf[f] = *reinterpret_cast<const bf16x8*>(Bb + boff[f]);
#pragma unroll
            for (int f = 0; f < 4; ++f) af[f] = *reinterpret_cast<const bf16x8*>(Ab + aoff[0][f]);
            if (pre) STAGE_A(nxt, 0, koff);
            __builtin_amdgcn_s_barrier();
            asm volatile("s_waitcnt lgkmcnt(0)" ::: "memory");
            __builtin_amdgcn_sched_barrier(0);
            __builtin_amdgcn_s_setprio(1);
#pragma unroll
            for (int f = 0; f < 4; ++f)
#pragma unroll
                for (int n = 0; n < 4; ++n)
                    acc[f][n] = __builtin_amdgcn_mfma_f32_16x16x32_bf16(af[f], bf[n], acc[f][n], 0, 0, 0);
            __builtin_amdgcn_s_setprio(0);
            __builtin_amdgcn_s_barrier();
        }
        // ================= phase 1: ks=0, mh=1 =================
        {
            const bf16* Ab = As + cur * 16384;
#pragma unroll
            for (int f = 0; f < 4; ++f) af[f] = *reinterpret_cast<const bf16x8*>(Ab + aoff[1][f]);
            if (pre) STAGE_B(nxt, 0, koff);
            // protect tile t's slab-1 (A,B): the 4 newest outstanding loads are t+1's s0.
            if (t == NT - 1) asm volatile("s_waitcnt vmcnt(0)" ::: "memory");
            else             asm volatile("s_waitcnt vmcnt(4)" ::: "memory");
            __builtin_amdgcn_s_barrier();
            asm volatile("s_waitcnt lgkmcnt(0)" ::: "memory");
            __builtin_amdgcn_sched_barrier(0);
            __builtin_amdgcn_s_setprio(1);
#pragma unroll
            for (int f = 0; f < 4; ++f)
#pragma unroll
                for (int n = 0; n < 4; ++n)
                    acc[4 + f][n] = __builtin_amdgcn_mfma_f32_16x16x32_bf16(af[f], bf[n], acc[4 + f][n], 0, 0, 0);
            __builtin_amdgcn_s_setprio(0);
            __builtin_amdgcn_s_barrier();
        }
        // ================= phase 2: ks=1, mh=0 =================
        {
            const bf16* Ab = As + cur * 16384 + 8192;
            const bf16* Bb = Bs + cur * 16384 + 8192;
#pragma unroll
            for (int f = 0; f < 4; ++f) bf[f] = *reinterpret_cast<const bf16x8*>(Bb + boff[f]);
#pragma unroll
            for (int f = 0; f < 4; ++f) af[f] = *reinterpret_cast<const bf16x8*>(Ab + aoff[0][f]);
            if (pre) STAGE_A(nxt, 1, koff);
            __builtin_amdgcn_s_barrier();
            asm volatile("s_waitcnt lgkmcnt(0)" ::: "memory");
            __builtin_amdgcn_sched_barrier(0);
            __builtin_amdgcn_s_setprio(1);
#pragma unroll
            for (int f = 0; f < 4; ++f)
#pragma unroll
                for (int n = 0; n < 4; ++n)
                    acc[f][n] = __builtin_amdgcn_mfma_f32_16x16x32_bf16(af[f], bf[n], acc[f][n], 0, 0, 0);
            __builtin_amdgcn_s_setprio(0);
            __builtin_amdgcn_s_barrier();
        }
        // ================= phase 3: ks=1, mh=1 =================
        {
            const bf16* Ab = As + cur * 16384 + 8192;
#pragma unroll
            for (int f = 0; f < 4; ++f) af[f] = *reinterpret_cast<const bf16x8*>(Ab + aoff[1][f]);
            if (pre) STAGE_B(nxt, 1, koff);
            // protect tile t+1's slab-0 (A,B): the 4 newest outstanding are t+1's s1.
            asm volatile("s_waitcnt vmcnt(4)" ::: "memory");
            __builtin_amdgcn_s_barrier();
            asm volatile("s_waitcnt lgkmcnt(0)" ::: "memory");
            __builtin_amdgcn_sched_barrier(0);
            __builtin_amdgcn_s_setprio(1);
#pragma unroll
            for (int f = 0; f < 4; ++f)
#pragma unroll
                for (int n = 0; n < 4; ++n)
                    acc[4 + f][n] = __builtin_amdgcn_mfma_f32_16x16x32_bf16(af[f], bf[n], acc[4 + f][n], 0, 0, 0);
            __builtin_amdgcn_s_setprio(0);
            __builtin_amdgcn_s_barrier();
        }
    }

    // ---- epilogue: C/D layout col=lane&15, row=q*4+r; add bias; fp32 store ----
#pragma unroll
    for (int mf = 0; mf < 8; ++mf) {
        const int gr = m0 + wm * 128 + (mf >> 2) * 64 + (mf & 3) * 16 + q * 4;
#pragma unroll
        for (int nf = 0; nf < 4; ++nf) {
            const int gc = n0 + wn * 64 + nf * 16 + r16;
            const float bv = bias[gc];
#pragma unroll
            for (int r = 0; r < 4; ++r)
                out[(size_t)(gr + r) * N + gc] = acc[mf][nf][r] + bv;
        }
    }
#undef STAGE_A
#undef STAGE_B
}

extern "C" void kernel_launch(void* const* d_in, const int* in_sizes, int n_in,
                              void* d_out, int out_size, void* d_ws, size_t ws_size,
                              hipStream_t stream) {
    const float* x    = (const float*)d_in[0];
    const float* base = (const float*)d_in[1];
    const float* lA   = (const float*)d_in[2];
    const float* lB   = (const float*)d_in[3];
    const float* bias = (const float*)d_in[4];
    float* out = (float*)d_out;

    const int  N    = in_sizes[4];             // d_out = 4096
    const int  rank = in_sizes[3] / N;         // 8
    const int  K    = in_sizes[2] / rank;      // d_in = 4096
    const long M    = (long)in_sizes[0] / K;   // 8192
    const float scale = 16.0f / (float)rank;   // alpha/rank = 2.0

    bf16* Xb = (bf16*)d_ws;
    bf16* Wb = Xb + (size_t)M * K;
    const size_t need = ((size_t)M * K + (size_t)N * K) * sizeof(bf16);
    if (ws_size < need) {
        fprintf(stderr, "kernel_launch: ws_size %zu < needed %zu\n", ws_size, need);
        return;
    }

    const long n8x = (long)M * K / 8;
    long blk = (n8x + 255) / 256;
    if (blk > 2048) blk = 2048;
    prep_x<<<dim3((unsigned)blk), dim3(256), 0, stream>>>(x, Xb, n8x);

    prep_w<<<dim3((unsigned)N), dim3(256), 0, stream>>>(base, lA, lB, Wb, K, rank, scale);

    gemm_8ph<<<dim3(N / BN, (unsigned)(M / BM)), dim3(512), 0, stream>>>(
        Xb, Wb, bias, out, (int)M, N, K);
}

// Round 3
// 541.917 us; speedup vs baseline: 1.0793x; 1.0018x over previous
//
#include <hip/hip_runtime.h>
#include <hip/hip_bf16.h>
#include <cstdio>

// LoRALinear: out[M,N] = x[M,K] @ W[N,K]^T + bias, W = base + (16/8)*(lora_B @ lora_A)
// M=8192, N=4096, K=4096 (fp32 in/out; internal bf16 MFMA).
// R7: R6's 8-phase hit 971 TF but MfmaUtil stuck at 42.5% (vs template 62%) -> latency
// stall: prefetch depth was 1 K-tile (~3-4 phases of cover vs ~200-900cy load latency),
// and vmcnt sat BEFORE the MFMA cluster. Fix: 6-phase-deep uniform issue schedule
// (1 unit = 2 gload_lds per phase; t+1.s1 at ph0/ph1 into nxt, t+2.s0 at ph2/ph3 into
// the RELEASED cur.s0 slots), vmcnt(8) after the MFMA of ph1/ph3 only (tail: 4/0), plus
// bijective XCD swizzle (512 blocks % 8 == 0). Preps frozen (residual ~260us is prep-
// structure-invariant across R4/R5/R6).

using bf16   = __bf16;
using bf16x8 = __attribute__((ext_vector_type(8))) __bf16;
using f32x4  = __attribute__((ext_vector_type(4))) float;

#define BM 256
#define BN 256
#define BK 64   // two K-slabs of 32

// ---------------- kernel 1a: x fp32 -> bf16 stream convert ----------------
__global__ __launch_bounds__(256) void prep_x(const float* __restrict__ x,
                                              bf16* __restrict__ Xb, long n8) {
    const long stride = (long)gridDim.x * blockDim.x;
    for (long i = (long)blockIdx.x * blockDim.x + threadIdx.x; i < n8; i += stride) {
        const float4 a = reinterpret_cast<const float4*>(x)[2 * i];
        const float4 b = reinterpret_cast<const float4*>(x)[2 * i + 1];
        bf16x8 o;
        o[0] = (bf16)a.x; o[1] = (bf16)a.y; o[2] = (bf16)a.z; o[3] = (bf16)a.w;
        o[4] = (bf16)b.x; o[5] = (bf16)b.y; o[6] = (bf16)b.z; o[7] = (bf16)b.w;
        reinterpret_cast<bf16x8*>(Xb)[i] = o;
    }
}

// ---------------- kernel 1b: W = base + scale*(B@A), fp32 -> bf16 ----------------
__global__ __launch_bounds__(256) void prep_w(const float* __restrict__ base,
                                              const float* __restrict__ A,
                                              const float* __restrict__ Bm,
                                              bf16* __restrict__ Wb,
                                              int K, int rank, float scale) {
    const int o = blockIdx.x;
    float br[8];
    const int rr = rank < 8 ? rank : 8;
    for (int r = 0; r < rr; ++r) br[r] = scale * Bm[(size_t)o * rank + r];

    const float* brow = base + (size_t)o * K;
    bf16*        wrow = Wb + (size_t)o * K;

    for (int c = threadIdx.x * 8; c < K; c += 256 * 8) {
        float4 s0 = *reinterpret_cast<const float4*>(brow + c);
        float4 s1 = *reinterpret_cast<const float4*>(brow + c + 4);
        if (rank == 8) {
#pragma unroll
            for (int r = 0; r < 8; ++r) {
                const float4 a0 = *reinterpret_cast<const float4*>(A + (size_t)r * K + c);
                const float4 a1 = *reinterpret_cast<const float4*>(A + (size_t)r * K + c + 4);
                s0.x += br[r] * a0.x; s0.y += br[r] * a0.y;
                s0.z += br[r] * a0.z; s0.w += br[r] * a0.w;
                s1.x += br[r] * a1.x; s1.y += br[r] * a1.y;
                s1.z += br[r] * a1.z; s1.w += br[r] * a1.w;
            }
        } else {
            for (int r = 0; r < rank; ++r) {
                const float b = scale * Bm[(size_t)o * rank + r];
                const float4 a0 = *reinterpret_cast<const float4*>(A + (size_t)r * K + c);
                const float4 a1 = *reinterpret_cast<const float4*>(A + (size_t)r * K + c + 4);
                s0.x += b * a0.x; s0.y += b * a0.y; s0.z += b * a0.z; s0.w += b * a0.w;
                s1.x += b * a1.x; s1.y += b * a1.y; s1.z += b * a1.z; s1.w += b * a1.w;
            }
        }
        bf16x8 ov;
        ov[0] = (bf16)s0.x; ov[1] = (bf16)s0.y; ov[2] = (bf16)s0.z; ov[3] = (bf16)s0.w;
        ov[4] = (bf16)s1.x; ov[5] = (bf16)s1.y; ov[6] = (bf16)s1.z; ov[7] = (bf16)s1.w;
        *reinterpret_cast<bf16x8*>(wrow + c) = ov;
    }
}

// ---------------- kernel 2: 256x256 8-phase bf16 GEMM, deep-pipelined ----------------
// LDS per matrix: [2 buf][2 kslab][256 rows][32 elems]; slab = 16KiB, staged by
// 2 global_load_lds x 16B per thread (linear dest). Swizzle: 16B chunk c of row r
// lives at slot c^((r>>1)&3) (source pre-swizzled). 8 waves 2Mx4N; per-wave C 128x64.
// Issue schedule (1 unit/phase, 6 phases ahead of consumption):
//   ph0: (t+1).A.s1  ph1: (t+1).B.s1  ph2: (t+2).A.s0->cur  ph3: (t+2).B.s0->cur
// vmcnt(8) after MFMA of ph1/ph3 (tail: vmcnt(4) at NT-2.ph3, vmcnt(0) at NT-1.ph1).
__global__ __launch_bounds__(512, 2) void gemm_8ph(
    const bf16* __restrict__ Xb,    // [M,K] row-major
    const bf16* __restrict__ Wb,    // [N,K] row-major
    const float* __restrict__ bias, // [N]
    float* __restrict__ out,        // [M,N] row-major fp32
    int M, int N, int K)
{
    __shared__ __align__(16) bf16 As[2 * 2 * 256 * 32];  // 64 KiB
    __shared__ __align__(16) bf16 Bs[2 * 2 * 256 * 32];  // 64 KiB

    const int tid  = threadIdx.x;     // 0..511
    const int lane = tid & 63;
    const int wv   = tid >> 6;        // wave 0..7
    const int wm   = wv >> 2;         // 0..1
    const int wn   = wv & 3;          // 0..3

    // ---- XCD-aware bijective block swizzle (T1): nwg=512, 512%8==0 ----
    const int nbx = gridDim.x;
    const int nwg = gridDim.x * gridDim.y;
    const int orig = blockIdx.y * nbx + blockIdx.x;
    const int swz = ((nwg & 7) == 0) ? ((orig & 7) * (nwg >> 3) + (orig >> 3)) : orig;
    const int m0 = (swz / nbx) * BM;
    const int n0 = (swz % nbx) * BN;

    const int r16 = lane & 15;        // row-in-16 for frags; col for C/D
    const int q   = lane >> 4;        // quad 0..3 -> K-chunk within slab
    const int cq  = (q ^ ((r16 >> 1) & 3)) * 8;  // swizzled elem offset in 32-wide row

    // ---- staging: slot(i)=i*512+tid; row=slot>>2; src chunk c = (tid&3)^((row>>1)&3)
    const bf16* srcA[2];
    const bf16* srcB[2];
#pragma unroll
    for (int i = 0; i < 2; ++i) {
        const int slot = i * 512 + tid;
        const int row  = slot >> 2;
        const int c    = (tid & 3) ^ ((row >> 1) & 3);
        srcA[i] = Xb + (size_t)(m0 + row) * K + c * 8;
        srcB[i] = Wb + (size_t)(n0 + row) * K + c * 8;
    }
    // wave-uniform LDS dest element offsets (within a slab)
    const int dst0 = (0 * 512 + wv * 64) * 8;
    const int dst1 = (1 * 512 + wv * 64) * 8;

#define STAGE_A(buf, kh, koff)                                                        \
    do {                                                                              \
        __builtin_amdgcn_global_load_lds(                                             \
            (const __attribute__((address_space(1))) void*)(srcA[0] + (koff) + (kh) * 32), \
            (__attribute__((address_space(3))) void*)(As + (buf) * 16384 + (kh) * 8192 + dst0), \
            16, 0, 0);                                                                \
        __builtin_amdgcn_global_load_lds(                                             \
            (const __attribute__((address_space(1))) void*)(srcA[1] + (koff) + (kh) * 32), \
            (__attribute__((address_space(3))) void*)(As + (buf) * 16384 + (kh) * 8192 + dst1), \
            16, 0, 0);                                                                \
    } while (0)
#define STAGE_B(buf, kh, koff)                                                        \
    do {                                                                              \
        __builtin_amdgcn_global_load_lds(                                             \
            (const __attribute__((address_space(1))) void*)(srcB[0] + (koff) + (kh) * 32), \
            (__attribute__((address_space(3))) void*)(Bs + (buf) * 16384 + (kh) * 8192 + dst0), \
            16, 0, 0);                                                                \
        __builtin_amdgcn_global_load_lds(                                             \
            (const __attribute__((address_space(1))) void*)(srcB[1] + (koff) + (kh) * 32), \
            (__attribute__((address_space(3))) void*)(Bs + (buf) * 16384 + (kh) * 8192 + dst1), \
            16, 0, 0);                                                                \
    } while (0)

    // ---- k-invariant fragment element offsets (within a slab) ----
    int aoff[2][4], boff[4];
#pragma unroll
    for (int mh = 0; mh < 2; ++mh)
#pragma unroll
        for (int f = 0; f < 4; ++f)
            aoff[mh][f] = (wm * 128 + mh * 64 + f * 16 + r16) * 32 + cq;
#pragma unroll
    for (int f = 0; f < 4; ++f)
        boff[f] = (wn * 64 + f * 16 + r16) * 32 + cq;

    f32x4 acc[8][4] = {};

    const int NT = K / BK;

    // ---- prologue: t0 fully + t1.s0; vmcnt(8) leaves {t0.s1, t1.s0} in flight ----
    STAGE_A(0, 0, 0);
    STAGE_B(0, 0, 0);
    STAGE_A(0, 1, 0);
    STAGE_B(0, 1, 0);
    if (NT > 1) {
        STAGE_A(1, 0, BK);
        STAGE_B(1, 0, BK);
        asm volatile("s_waitcnt vmcnt(8)" ::: "memory");
    } else {
        asm volatile("s_waitcnt vmcnt(4)" ::: "memory");
    }
    __builtin_amdgcn_s_barrier();

    for (int t = 0; t < NT; ++t) {
        const int cur   = t & 1;
        const int nxt   = cur ^ 1;
        const int koff1 = (t + 1) * BK;
        const int koff2 = (t + 2) * BK;
        const bool pre1 = (t + 1 < NT);
        const bool pre2 = (t + 2 < NT);
        bf16x8 bf[4], af[4];

        // ================= phase 0: ks=0, mh=0 =================
        {
            const bf16* Ab = As + cur * 16384;
            const bf16* Bb = Bs + cur * 16384;
#pragma unroll
            for (int f = 0; f < 4; ++f) bf[f] = *reinterpret_cast<const bf16x8*>(Bb + boff[f]);
#pragma unroll
            for (int f = 0; f < 4; ++f) af[f] = *reinterpret_cast<const bf16x8*>(Ab + aoff[0][f]);
            if (pre1) STAGE_A(nxt, 1, koff1);                 // (t+1).A.s1
            __builtin_amdgcn_s_barrier();
            asm volatile("s_waitcnt lgkmcnt(0)" ::: "memory");
            __builtin_amdgcn_sched_barrier(0);
            __builtin_amdgcn_s_setprio(1);
#pragma unroll
            for (int f = 0; f < 4; ++f)
#pragma unroll
                for (int n = 0; n < 4; ++n)
                    acc[f][n] = __builtin_amdgcn_mfma_f32_16x16x32_bf16(af[f], bf[n], acc[f][n], 0, 0, 0);
            __builtin_amdgcn_s_setprio(0);
            __builtin_amdgcn_s_barrier();
        }
        // ================= phase 1: ks=0, mh=1 =================
        {
            const bf16* Ab = As + cur * 16384;
#pragma unroll
            for (int f = 0; f < 4; ++f) af[f] = *reinterpret_cast<const bf16x8*>(Ab + aoff[1][f]);
            if (pre1) STAGE_B(nxt, 1, koff1);                 // (t+1).B.s1
            __builtin_amdgcn_s_barrier();
            asm volatile("s_waitcnt lgkmcnt(0)" ::: "memory");
            __builtin_amdgcn_sched_barrier(0);
            __builtin_amdgcn_s_setprio(1);
#pragma unroll
            for (int f = 0; f < 4; ++f)
#pragma unroll
                for (int n = 0; n < 4; ++n)
                    acc[4 + f][n] = __builtin_amdgcn_mfma_f32_16x16x32_bf16(af[f], bf[n], acc[4 + f][n], 0, 0, 0);
            __builtin_amdgcn_s_setprio(0);
            // protect t.ph2 reads (cur.s1): newer issues = {t-1.ph2, t-1.ph3, t.ph0, t.ph1} = 8
            if (t == NT - 1) asm volatile("s_waitcnt vmcnt(0)" ::: "memory");
            else             asm volatile("s_waitcnt vmcnt(8)" ::: "memory");
            __builtin_amdgcn_s_barrier();
        }
        // ================= phase 2: ks=1, mh=0 =================
        {
            const bf16* Ab = As + cur * 16384 + 8192;
            const bf16* Bb = Bs + cur * 16384 + 8192;
#pragma unroll
            for (int f = 0; f < 4; ++f) bf[f] = *reinterpret_cast<const bf16x8*>(Bb + boff[f]);
#pragma unroll
            for (int f = 0; f < 4; ++f) af[f] = *reinterpret_cast<const bf16x8*>(Ab + aoff[0][f]);
            if (pre2) STAGE_A(cur, 0, koff2);                 // (t+2).A.s0 -> released cur.s0
            __builtin_amdgcn_s_barrier();
            asm volatile("s_waitcnt lgkmcnt(0)" ::: "memory");
            __builtin_amdgcn_sched_barrier(0);
            __builtin_amdgcn_s_setprio(1);
#pragma unroll
            for (int f = 0; f < 4; ++f)
#pragma unroll
                for (int n = 0; n < 4; ++n)
                    acc[f][n] = __builtin_amdgcn_mfma_f32_16x16x32_bf16(af[f], bf[n], acc[f][n], 0, 0, 0);
            __builtin_amdgcn_s_setprio(0);
            __builtin_amdgcn_s_barrier();
        }
        // ================= phase 3: ks=1, mh=1 =================
        {
            const bf16* Ab = As + cur * 16384 + 8192;
#pragma unroll
            for (int f = 0; f < 4; ++f) af[f] = *reinterpret_cast<const bf16x8*>(Ab + aoff[1][f]);
            if (pre2) STAGE_B(cur, 0, koff2);                 // (t+2).B.s0 -> released cur.s0
            __builtin_amdgcn_s_barrier();
            asm volatile("s_waitcnt lgkmcnt(0)" ::: "memory");
            __builtin_amdgcn_sched_barrier(0);
            __builtin_amdgcn_s_setprio(1);
#pragma unroll
            for (int f = 0; f < 4; ++f)
#pragma unroll
                for (int n = 0; n < 4; ++n)
                    acc[4 + f][n] = __builtin_amdgcn_mfma_f32_16x16x32_bf16(af[f], bf[n], acc[4 + f][n], 0, 0, 0);
            __builtin_amdgcn_s_setprio(0);
            // protect (t+1).ph0 reads ((t+1).s0): newer issues = {t.ph0, t.ph1, t.ph2, t.ph3} = 8
            if (t == NT - 2)     asm volatile("s_waitcnt vmcnt(4)" ::: "memory");
            else if (t < NT - 2) asm volatile("s_waitcnt vmcnt(8)" ::: "memory");
            // t == NT-1: nothing left to protect
            __builtin_amdgcn_s_barrier();
        }
    }

    // ---- epilogue: C/D layout col=lane&15, row=q*4+r; add bias; fp32 store ----
#pragma unroll
    for (int mf = 0; mf < 8; ++mf) {
        const int gr = m0 + wm * 128 + (mf >> 2) * 64 + (mf & 3) * 16 + q * 4;
#pragma unroll
        for (int nf = 0; nf < 4; ++nf) {
            const int gc = n0 + wn * 64 + nf * 16 + r16;
            const float bv = bias[gc];
#pragma unroll
            for (int r = 0; r < 4; ++r)
                out[(size_t)(gr + r) * N + gc] = acc[mf][nf][r] + bv;
        }
    }
#undef STAGE_A
#undef STAGE_B
}

extern "C" void kernel_launch(void* const* d_in, const int* in_sizes, int n_in,
                              void* d_out, int out_size, void* d_ws, size_t ws_size,
                              hipStream_t stream) {
    const float* x    = (const float*)d_in[0];
    const float* base = (const float*)d_in[1];
    const float* lA   = (const float*)d_in[2];
    const float* lB   = (const float*)d_in[3];
    const float* bias = (const float*)d_in[4];
    float* out = (float*)d_out;

    const int  N    = in_sizes[4];             // d_out = 4096
    const int  rank = in_sizes[3] / N;         // 8
    const int  K    = in_sizes[2] / rank;      // d_in = 4096
    const long M    = (long)in_sizes[0] / K;   // 8192
    const float scale = 16.0f / (float)rank;   // alpha/rank = 2.0

    bf16* Xb = (bf16*)d_ws;
    bf16* Wb = Xb + (size_t)M * K;
    const size_t need = ((size_t)M * K + (size_t)N * K) * sizeof(bf16);
    if (ws_size < need) {
        fprintf(stderr, "kernel_launch: ws_size %zu < needed %zu\n", ws_size, need);
        return;
    }

    const long n8x = (long)M * K / 8;
    long blk = (n8x + 255) / 256;
    if (blk > 2048) blk = 2048;
    prep_x<<<dim3((unsigned)blk), dim3(256), 0, stream>>>(x, Xb, n8x);

    prep_w<<<dim3((unsigned)N), dim3(256), 0, stream>>>(base, lA, lB, Wb, K, rank, scale);

    gemm_8ph<<<dim3(N / BN, (unsigned)(M / BM)), dim3(512), 0, stream>>>(
        Xb, Wb, bias, out, (int)M, N, K);
}